// Round 1
// baseline (254.202 us; speedup 1.0000x reference)
//
#include <hip/hip_runtime.h>

// Elements per block / per wave. B = 16777216 → NB = 2048 blocks.
#define E_BLOCK 8192
#define E_WAVE  2048          // E_BLOCK / 4 waves
#define ITERS   16            // E_WAVE / (64 lanes * 2 elems)

#define M1      0.2771814156f // 0.5*(85/900)^0.25  (class-1 LDAM margin)
#define LDAM_S  30.0f

struct BlockRec {
  int s0, p0, s1, p1;   // chain state per class: sum + packed(first|last<<1|ne<<2)
  float wnll, fl;
  int cnt1, pad;
};

// Ordered chain-state combine: A (in sa/pa) followed by B (sb/pb).
// pk==0 means empty. bit0: first>0, bit1: last>0, bit2: nonempty.
__device__ __forceinline__ void comb(int &sa, int &pa, int sb, int pb) {
  if (pa == 0) { sa = sb; pa = pb; }
  else if (pb != 0) {
    int la = ((pa >> 1) & 1) * 2 - 1;   // last sign of A
    int fb = (pb & 1) * 2 - 1;          // first sign of B
    sa += sb + la * fb;
    pa = 4 | (pa & 1) | (pb & 2);
  }
}

__global__ __launch_bounds__(256) void loss_pass1(
    const float* __restrict__ x, const int* __restrict__ tgt,
    BlockRec* __restrict__ recs, int B) {
  const int w    = threadIdx.x >> 6;
  const int lane = threadIdx.x & 63;
  const int waveBase = blockIdx.x * E_BLOCK + w * E_WAVE;  // wave owns contiguous range

  float wnll = 0.f, fls = 0.f;
  int cnt1 = 0;
  int rs0 = 0, rp0 = 0, rs1 = 0, rp1 = 0;  // running chain state (identical on all lanes)

  for (int j = 0; j < ITERS; ++j) {
    const int e = waveBase + ((j << 6) + lane) * 2;  // this thread's 2 consecutive elements
    int ps0 = 0, pp0 = 0, ps1 = 0, pp1 = 0;
    if (e < B) {  // B is even; e<B implies e+1<B
      const float4 xv = *reinterpret_cast<const float4*>(x + 2 * e);
      const int2  tv = *reinterpret_cast<const int2*>(tgt + e);
      int sA, sB;
      {
        const float x0 = xv.x, x1 = xv.y; const int t = tv.x;
        const float d  = t ? LDAM_S * (x0 - x1 + M1) : LDAM_S * (x1 - x0 + 0.5f);
        const float sp = fmaxf(d, 0.f) + __logf(1.f + __expf(-fabsf(d)));  // softplus
        wnll += (t ? 0.85f : 0.15f) * sp;
        fls  += t ? (-0.85f * (1.f - x1) * (1.f - x1) * __logf(x1 + 1e-9f))
                  : (-0.15f * x1 * x1 * __logf(1.f - x1 + 1e-9f));
        cnt1 += t;
        sA = (x0 > x1) ? 1 : -1;
      }
      {
        const float x0 = xv.z, x1 = xv.w; const int t = tv.y;
        const float d  = t ? LDAM_S * (x0 - x1 + M1) : LDAM_S * (x1 - x0 + 0.5f);
        const float sp = fmaxf(d, 0.f) + __logf(1.f + __expf(-fabsf(d)));
        wnll += (t ? 0.85f : 0.15f) * sp;
        fls  += t ? (-0.85f * (1.f - x1) * (1.f - x1) * __logf(x1 + 1e-9f))
                  : (-0.15f * x1 * x1 * __logf(1.f - x1 + 1e-9f));
        cnt1 += t;
        sB = (x0 > x1) ? 1 : -1;
      }
      // 2-element pair states per class
      const int bA = (sA > 0), bB = (sB > 0);
      const bool a0 = (tv.x == 0), b0 = (tv.y == 0);
      if (a0 && b0)      { ps0 = sA * sB; pp0 = 4 | bA | (bB << 1); }
      else if (a0)       { pp0 = 4 | bA | (bA << 1); }
      else if (b0)       { pp0 = 4 | bB | (bB << 1); }
      if (!a0 && !b0)    { ps1 = sA * sB; pp1 = 4 | bA | (bB << 1); }
      else if (!a0)      { pp1 = 4 | bA | (bA << 1); }
      else if (!b0)      { pp1 = 4 | bB | (bB << 1); }
    }
    // Order-preserving butterfly: after 6 steps every lane holds the combined
    // state of the wave's 128 contiguous elements in index order.
    #pragma unroll
    for (int k = 0; k < 6; ++k) {
      const int m = 1 << k;
      const int os0 = __shfl_xor(ps0, m), op0 = __shfl_xor(pp0, m);
      const int os1 = __shfl_xor(ps1, m), op1 = __shfl_xor(pp1, m);
      const bool up = (lane & m) != 0;
      int fs = up ? os0 : ps0, fp = up ? op0 : pp0;
      int gs = up ? ps0 : os0, gp = up ? pp0 : op0;
      comb(fs, fp, gs, gp); ps0 = fs; pp0 = fp;
      fs = up ? os1 : ps1; fp = up ? op1 : pp1;
      gs = up ? ps1 : os1; gp = up ? pp1 : op1;
      comb(fs, fp, gs, gp); ps1 = fs; pp1 = fp;
    }
    comb(rs0, rp0, ps0, pp0);
    comb(rs1, rp1, ps1, pp1);
  }

  // commutative wave reductions for the scalar partials
  #pragma unroll
  for (int k = 1; k < 64; k <<= 1) {
    wnll += __shfl_xor(wnll, k);
    fls  += __shfl_xor(fls, k);
    cnt1 += __shfl_xor(cnt1, k);
  }

  __shared__ int   shi[4][5];
  __shared__ float shf[4][2];
  if (lane == 0) {
    shi[w][0] = rs0; shi[w][1] = rp0; shi[w][2] = rs1; shi[w][3] = rp1; shi[w][4] = cnt1;
    shf[w][0] = wnll; shf[w][1] = fls;
  }
  __syncthreads();
  if (threadIdx.x == 0) {
    int S0 = 0, P0 = 0, S1 = 0, P1 = 0, C = 0; float W = 0.f, F = 0.f;
    #pragma unroll
    for (int q = 0; q < 4; ++q) {   // waves in ascending element order
      comb(S0, P0, shi[q][0], shi[q][1]);
      comb(S1, P1, shi[q][2], shi[q][3]);
      C += shi[q][4]; W += shf[q][0]; F += shf[q][1];
    }
    BlockRec r; r.s0 = S0; r.p0 = P0; r.s1 = S1; r.p1 = P1;
    r.wnll = W; r.fl = F; r.cnt1 = C; r.pad = 0;
    recs[blockIdx.x] = r;
  }
}

__global__ __launch_bounds__(64) void loss_pass2(
    const BlockRec* __restrict__ recs, int NB, int B, float* __restrict__ out) {
  const int lane = threadIdx.x;
  const int G = (NB + 63) >> 6;
  int s0 = 0, p0 = 0, s1 = 0, p1 = 0;
  double W = 0.0, F = 0.0;
  long long C = 0;
  for (int g = 0; g < G; ++g) {
    const int b = lane * G + g;   // lane-contiguous → ascending block order across lanes
    if (b < NB) {
      const BlockRec r = recs[b];
      comb(s0, p0, r.s0, r.p0);
      comb(s1, p1, r.s1, r.p1);
      W += (double)r.wnll; F += (double)r.fl; C += r.cnt1;
    }
  }
  #pragma unroll
  for (int k = 0; k < 6; ++k) {
    const int m = 1 << k;
    const int os0 = __shfl_xor(s0, m), op0 = __shfl_xor(p0, m);
    const int os1 = __shfl_xor(s1, m), op1 = __shfl_xor(p1, m);
    const double oW = __shfl_xor(W, m), oF = __shfl_xor(F, m);
    const long long oC = __shfl_xor(C, m);
    const bool up = (lane & m) != 0;
    int fs = up ? os0 : s0, fp = up ? op0 : p0;
    int gs = up ? s0 : os0, gp = up ? p0 : op0;
    comb(fs, fp, gs, gp); s0 = fs; p0 = fp;
    fs = up ? os1 : s1; fp = up ? op1 : p1;
    gs = up ? s1 : os1; gp = up ? p1 : op1;
    comb(fs, fp, gs, gp); s1 = fs; p1 = fp;
    W += oW; F += oF; C += oC;
  }
  if (lane == 0) {
    const double n1 = (double)C, n0 = (double)B - n1;
    const double sw = 0.15 * n0 + 0.85 * n1;
    const double ldam  = W / sw;
    const double focal = F / (double)B;
    const double q0 = (n0 > 0.0) ? (double)s0 / n0 : 0.0;
    const double q1 = (n1 > 0.0) ? (double)s1 / n1 : 0.0;
    const double dq = q0 - q1;
    out[0] = (float)(ldam + focal + dq * dq);
  }
}

extern "C" void kernel_launch(void* const* d_in, const int* in_sizes, int n_in,
                              void* d_out, int out_size, void* d_ws, size_t ws_size,
                              hipStream_t stream) {
  const float* x  = (const float*)d_in[0];
  const int* tgt  = (const int*)d_in[1];
  float* out      = (float*)d_out;
  const int B  = in_sizes[1];                       // row count (16777216)
  const int NB = (B + E_BLOCK - 1) / E_BLOCK;       // 2048
  BlockRec* recs = (BlockRec*)d_ws;                 // NB * 32 B = 64 KB scratch
  loss_pass1<<<NB, 256, 0, stream>>>(x, tgt, recs, B);
  loss_pass2<<<1, 64, 0, stream>>>(recs, NB, B, out);
}

// Round 2
// 245.030 us; speedup vs baseline: 1.0374x; 1.0374x over previous
//
#include <hip/hip_runtime.h>

// B = 16777216 rows, 2 cols. 2048 blocks x 8192 elems.
#define E_BLOCK 8192
#define E_WAVE  2048
#define ITERS   16            // E_WAVE / (64 lanes * 2 elems)

#define M1      0.2771814156f // 0.5*(85/900)^0.25  (class-1 LDAM margin)
#define LDAM_S  30.0f

struct BlockRec {
  int s0, p0, s1, p1;   // chain sum + packed (f+1) | (l+1)<<4 per class
  float wnll, fl;
  int cnt1, pad;
};

// 0-encoded chain state: f==0 => empty (then s==0, l==0). f,l in {-1,0,+1}.
// Ordered combine: (s,f,l) := (s,f,l) ++ (sb,fb,lb). Branchless.
__device__ __forceinline__ void comb0(int &s, int &f, int &l, int sb, int fb, int lb) {
  s += sb + l * fb;        // cross term is 0 if either side empty (l==0 or fb==0)
  f = f ? f : fb;
  l = fb ? lb : l;
}

__device__ __forceinline__ void bfly_step(int m, int lane, int &s, int &f, int &l) {
  const int os = __shfl_xor(s, m), of = __shfl_xor(f, m), ol = __shfl_xor(l, m);
  const bool up = (lane & m) != 0;
  int as = up ? os : s, af = up ? of : f, al = up ? ol : l;
  const int bs = up ? s : os, bf = up ? f : of, bl = up ? l : ol;
  comb0(as, af, al, bs, bf, bl);
  s = as; f = af; l = al;
}

__global__ __launch_bounds__(256) void loss_pass1(
    const float* __restrict__ x, const int* __restrict__ tgt,
    BlockRec* __restrict__ recs, int B) {
  // LDS layout (words): [0,2304) chunk bytes (thread t owns words 9t..9t+7, 1 pad
  // word breaks bank alignment); [2304,2560) packed states; [2560,2816) wnll;
  // [2816,3072) fls; [3072,3328) cnt.
  __shared__ unsigned int lds[3328];
  unsigned int* chunkw = lds;
  unsigned int* stw = lds + 2304;
  float* wnw = (float*)(lds + 2560);
  float* flw = (float*)(lds + 2816);
  int*   cnw = (int*)(lds + 3072);
  unsigned short* cs = (unsigned short*)lds;   // stride-18 shorts per chunk

  const int tid = threadIdx.x;
  const int w = tid >> 6, lane = tid & 63;
  const int waveBase = blockIdx.x * E_BLOCK + w * E_WAVE;

  float wnll = 0.f, fls = 0.f; int cnt1 = 0;

  for (int j = 0; j < ITERS; ++j) {
    const int e = waveBase + ((j << 6) + lane) * 2;
    unsigned int pk = 0;
    if (e < B) {   // B even: e<B implies e+1<B
      const float4 xv = *reinterpret_cast<const float4*>(x + 2 * e);
      const int2  tv = *reinterpret_cast<const int2*>(tgt + e);
      unsigned int c[2];
      const float x0a = xv.x, x1a = xv.y; const float x0b = xv.z, x1b = xv.w;
      const int ta = tv.x, tb = tv.y;
      // elem A
      {
        const float d  = x0a - x1a;
        const float z  = LDAM_S * (ta ? (d + M1) : (0.5f - d));
        const float sp = fmaxf(z, 0.f) + __logf(1.f + __expf(-fabsf(z)));
        wnll += (ta ? 0.85f : 0.15f) * sp;
        const float p  = x1a;
        const float lg = __logf((ta ? p : (1.f - p)) + 1e-9f);
        const float cf = ta ? (-0.85f * (1.f - p) * (1.f - p)) : (-0.15f * p * p);
        fls += cf * lg;
        cnt1 += ta;
        c[0] = 4u | (unsigned)(x0a > x1a) | ((unsigned)ta << 1);
      }
      // elem B
      {
        const float d  = x0b - x1b;
        const float z  = LDAM_S * (tb ? (d + M1) : (0.5f - d));
        const float sp = fmaxf(z, 0.f) + __logf(1.f + __expf(-fabsf(z)));
        wnll += (tb ? 0.85f : 0.15f) * sp;
        const float p  = x1b;
        const float lg = __logf((tb ? p : (1.f - p)) + 1e-9f);
        const float cf = tb ? (-0.85f * (1.f - p) * (1.f - p)) : (-0.15f * p * p);
        fls += cf * lg;
        cnt1 += tb;
        c[1] = 4u | (unsigned)(x0b > x1b) | ((unsigned)tb << 1);
      }
      pk = c[0] | (c[1] << 8);
    }
    // element-pair local index; owner thread = li>>5, col = (li>>1)&15
    const int li2 = w * 1024 + (j << 6) + lane;
    cs[(li2 >> 4) * 18 + (li2 & 15)] = (unsigned short)pk;
  }
  __syncthreads();

  // Phase 2: each thread serially chains its contiguous 32-element chunk.
  int s0 = 0, f0 = 0, l0 = 0, s1 = 0, f1 = 0, l1 = 0;
  #pragma unroll
  for (int r = 0; r < 8; ++r) {
    const unsigned int wv = chunkw[tid * 9 + r];
    #pragma unroll
    for (int k = 0; k < 4; ++k) {
      const unsigned int b = (wv >> (8 * k)) & 7u;
      if (b & 4u) {
        const int sv = (int)((b & 1u) << 1) - 1;
        const int t  = (int)((b >> 1) & 1u);
        const int lv = t ? l1 : l0;
        const int add = lv * sv;        // 0 while class empty
        if (t) { s1 += add; l1 = sv; f1 = f1 ? f1 : sv; }
        else   { s0 += add; l0 = sv; f0 = f0 ? f0 : sv; }
      }
    }
  }
  // Stage per-thread results; wave 0 does the single block combine.
  stw[tid] = (unsigned)(s0 + 128) | ((unsigned)(f0 + 1) << 8) | ((unsigned)(l0 + 1) << 10)
           | ((unsigned)(s1 + 128) << 16) | ((unsigned)(f1 + 1) << 24) | ((unsigned)(l1 + 1) << 26);
  wnw[tid] = wnll; flw[tid] = fls; cnw[tid] = cnt1;
  __syncthreads();

  if (w == 0) {
    int S0 = 0, F0 = 0, L0 = 0, S1 = 0, F1 = 0, L1 = 0;
    float W = 0.f, F = 0.f; int C = 0;
    #pragma unroll
    for (int q = 0; q < 4; ++q) {
      const int i = lane * 4 + q;                 // ascending thread (element) order
      const unsigned int pk = stw[i];
      comb0(S0, F0, L0, (int)(pk & 255u) - 128, (int)((pk >> 8) & 3u) - 1, (int)((pk >> 10) & 3u) - 1);
      comb0(S1, F1, L1, (int)((pk >> 16) & 255u) - 128, (int)((pk >> 24) & 3u) - 1, (int)((pk >> 26) & 3u) - 1);
      W += wnw[i]; F += flw[i]; C += cnw[i];
    }
    #pragma unroll
    for (int k = 0; k < 6; ++k) {
      const int m = 1 << k;
      bfly_step(m, lane, S0, F0, L0);
      bfly_step(m, lane, S1, F1, L1);
      W += __shfl_xor(W, m); F += __shfl_xor(F, m); C += __shfl_xor(C, m);
    }
    if (lane == 0) {
      BlockRec r;
      r.s0 = S0; r.p0 = (F0 + 1) | ((L0 + 1) << 4);
      r.s1 = S1; r.p1 = (F1 + 1) | ((L1 + 1) << 4);
      r.wnll = W; r.fl = F; r.cnt1 = C; r.pad = 0;
      recs[blockIdx.x] = r;
    }
  }
}

__global__ __launch_bounds__(256) void loss_pass2(
    const BlockRec* __restrict__ recs, int NB, int B, float* __restrict__ out) {
  __shared__ int sS0[256], sF0[256], sL0[256], sS1[256], sF1[256], sL1[256], sC[256];
  __shared__ double sW[256], sFl[256];
  const int tid = threadIdx.x, w = tid >> 6, lane = tid & 63;
  const int R = (NB + 255) >> 8;

  int s0 = 0, f0 = 0, l0 = 0, s1 = 0, f1 = 0, l1 = 0;
  double W = 0.0, Fd = 0.0; int C = 0;
  for (int r = 0; r < R; ++r) {
    const int b = tid * R + r;     // thread-contiguous chunks, ascending block order
    if (b < NB) {
      const BlockRec rec = recs[b];
      comb0(s0, f0, l0, rec.s0, (rec.p0 & 3) - 1, ((rec.p0 >> 4) & 3) - 1);
      comb0(s1, f1, l1, rec.s1, (rec.p1 & 3) - 1, ((rec.p1 >> 4) & 3) - 1);
      W += (double)rec.wnll; Fd += (double)rec.fl; C += rec.cnt1;
    }
  }
  sS0[tid] = s0; sF0[tid] = f0; sL0[tid] = l0;
  sS1[tid] = s1; sF1[tid] = f1; sL1[tid] = l1;
  sC[tid] = C; sW[tid] = W; sFl[tid] = Fd;
  __syncthreads();

  if (w == 0) {
    int S0 = 0, F0 = 0, L0 = 0, S1 = 0, F1 = 0, L1 = 0; int Ct = 0;
    double Wt = 0.0, Ft = 0.0;
    #pragma unroll
    for (int q = 0; q < 4; ++q) {
      const int i = lane * 4 + q;
      comb0(S0, F0, L0, sS0[i], sF0[i], sL0[i]);
      comb0(S1, F1, L1, sS1[i], sF1[i], sL1[i]);
      Wt += sW[i]; Ft += sFl[i]; Ct += sC[i];
    }
    #pragma unroll
    for (int k = 0; k < 6; ++k) {
      const int m = 1 << k;
      bfly_step(m, lane, S0, F0, L0);
      bfly_step(m, lane, S1, F1, L1);
      Wt += __shfl_xor(Wt, m); Ft += __shfl_xor(Ft, m); Ct += __shfl_xor(Ct, m);
    }
    if (lane == 0) {
      const double n1 = (double)Ct, n0 = (double)B - n1;
      const double sw = 0.15 * n0 + 0.85 * n1;
      const double ldam  = Wt / sw;
      const double focal = Ft / (double)B;
      const double q0 = (n0 > 0.0) ? (double)S0 / n0 : 0.0;
      const double q1 = (n1 > 0.0) ? (double)S1 / n1 : 0.0;
      const double dq = q0 - q1;
      out[0] = (float)(ldam + focal + dq * dq);
    }
  }
}

extern "C" void kernel_launch(void* const* d_in, const int* in_sizes, int n_in,
                              void* d_out, int out_size, void* d_ws, size_t ws_size,
                              hipStream_t stream) {
  const float* x  = (const float*)d_in[0];
  const int* tgt  = (const int*)d_in[1];
  float* out      = (float*)d_out;
  const int B  = in_sizes[1];                       // rows (16777216)
  const int NB = (B + E_BLOCK - 1) / E_BLOCK;       // 2048
  BlockRec* recs = (BlockRec*)d_ws;                 // 64 KB scratch
  loss_pass1<<<NB, 256, 0, stream>>>(x, tgt, recs, B);
  loss_pass2<<<1, 256, 0, stream>>>(recs, NB, B, out);
}